// Round 3
// baseline (530.373 us; speedup 1.0000x reference)
//
#include <hip/hip_runtime.h>

// Problem constants
#define DD   512
#define KK_N 32
#define HH   4
#define DH   128
#define BN_TOT 4096

// ---------------------------------------------------------------------------
// Batched SGEMM, C[r][o] = sum_k A[r*lda+k] * Bop[o][k] (+ bias[o])
//   BT=true : B stored [N][K] row-major (B[o*ldb+k])   — "NT"
//   BT=false: B stored [K][N] row-major (B[k*ldb+o])   — "NN"
// 256 threads. Tile BMxBN, per-thread TMxTN, K-chunk 16.
// Requires (BM/TM)*(BN/TN)==256, TM,TN multiples of 4, dims multiples of tile.
// ---------------------------------------------------------------------------
template<bool BT, int BM, int BN, int TM, int TN>
__global__ __launch_bounds__(256)
void sgemm(const float* __restrict__ A, int lda, int batchA,
           const float* __restrict__ B, int ldb, int batchB,
           float* __restrict__ C, int ldc, int batchC,
           const float* __restrict__ bias, int batchBias,
           int Kd)
{
    constexpr int BK = 16;
    constexpr int KG = BK / 4;              // float4 groups per k-chunk
    constexpr int A_LOADS = (BM * BK) / (4 * 256);
    constexpr int B_LOADS = (BN * BK) / (4 * 256);
    constexpr int NTX = BN / TN;            // threads along N

    const int bz = blockIdx.z;
    A += (long)bz * batchA;
    B += (long)bz * batchB;
    C += (long)bz * batchC;
    if (bias) bias += (long)bz * batchBias;

    __shared__ __align__(16) float As[BK][BM + 4];
    __shared__ __align__(16) float Bs[BK][BN + 4];

    const int t  = threadIdx.x;
    const int tx = t % NTX;                 // output col group (tx*TN)
    const int ty = t / NTX;                 // output row group (ty*TM)
    const int rbase = blockIdx.y * BM;
    const int obase = blockIdx.x * BN;

    float acc[TM][TN] = {};

    for (int k0 = 0; k0 < Kd; k0 += BK) {
        // ---- global loads for this chunk (to regs) ----
        float4 av[A_LOADS], bv[B_LOADS];
#pragma unroll
        for (int i = 0; i < A_LOADS; i++) {
            int s = t + i * 256;
            int row = s / KG, kg = s % KG;
            av[i] = *(const float4*)&A[(long)(rbase + row) * lda + k0 + kg * 4];
        }
#pragma unroll
        for (int i = 0; i < B_LOADS; i++) {
            int s = t + i * 256;
            if (BT) {
                int row = s / KG, kg = s % KG;
                bv[i] = *(const float4*)&B[(long)(obase + row) * ldb + k0 + kg * 4];
            } else {
                int kr = s / (BN / 4), oc = s % (BN / 4);
                bv[i] = *(const float4*)&B[(long)(k0 + kr) * ldb + obase + oc * 4];
            }
        }
        __syncthreads();   // previous chunk's LDS reads must be complete
        // ---- stage to LDS ----
#pragma unroll
        for (int i = 0; i < A_LOADS; i++) {
            int s = t + i * 256;
            int row = s / KG, kg = s % KG;
            const float* ap = (const float*)&av[i];
#pragma unroll
            for (int j = 0; j < 4; j++) As[kg * 4 + j][row] = ap[j];
        }
#pragma unroll
        for (int i = 0; i < B_LOADS; i++) {
            int s = t + i * 256;
            if (BT) {
                int row = s / KG, kg = s % KG;
                const float* bp = (const float*)&bv[i];
#pragma unroll
                for (int j = 0; j < 4; j++) Bs[kg * 4 + j][row] = bp[j];
            } else {
                int kr = s / (BN / 4), oc = s % (BN / 4);
                *(float4*)&Bs[kr][oc * 4] = bv[i];
            }
        }
        __syncthreads();
        // ---- compute ----
#pragma unroll
        for (int kk = 0; kk < BK; kk++) {
            float a[TM], b[TN];
#pragma unroll
            for (int im = 0; im < TM / 4; im++) {
                float4 v = *(const float4*)&As[kk][ty * TM + im * 4];
                a[im*4+0] = v.x; a[im*4+1] = v.y; a[im*4+2] = v.z; a[im*4+3] = v.w;
            }
#pragma unroll
            for (int in = 0; in < TN / 4; in++) {
                float4 v = *(const float4*)&Bs[kk][tx * TN + in * 4];
                b[in*4+0] = v.x; b[in*4+1] = v.y; b[in*4+2] = v.z; b[in*4+3] = v.w;
            }
#pragma unroll
            for (int i = 0; i < TM; i++)
#pragma unroll
                for (int j = 0; j < TN; j++)
                    acc[i][j] = fmaf(a[i], b[j], acc[i][j]);
        }
    }

    // ---- epilogue ----
    float bb[TN];
#pragma unroll
    for (int j = 0; j < TN; j++) bb[j] = 0.f;
    if (bias) {
#pragma unroll
        for (int in = 0; in < TN / 4; in++) {
            float4 v = *(const float4*)&bias[obase + tx * TN + in * 4];
            bb[in*4+0] = v.x; bb[in*4+1] = v.y; bb[in*4+2] = v.z; bb[in*4+3] = v.w;
        }
    }
#pragma unroll
    for (int i = 0; i < TM; i++) {
#pragma unroll
        for (int in = 0; in < TN / 4; in++) {
            float4 o;
            o.x = acc[i][in*4+0] + bb[in*4+0];
            o.y = acc[i][in*4+1] + bb[in*4+1];
            o.z = acc[i][in*4+2] + bb[in*4+2];
            o.w = acc[i][in*4+3] + bb[in*4+3];
            *(float4*)&C[(long)(rbase + ty * TM + i) * ldc + obase + tx * TN + in * 4] = o;
        }
    }
}

// ---------------------------------------------------------------------------
// Fused scores -> masked online softmax -> attention-weighted embedding sum.
// One block per (b,n). wne may alias g (read fully before written, same block).
// ---------------------------------------------------------------------------
__global__ __launch_bounds__(256)
void attn_fused(const float* __restrict__ ne,    // [BN][32][512]
                const int*   __restrict__ mask,  // [BN][32]
                const float* __restrict__ q,     // [BN][512]
                const float* g,                  // [BN][4][512]  (no restrict: aliases wne)
                const float* __restrict__ bk,    // [512]
                float* wne)                      // [BN][4][512]
{
    const int bn   = blockIdx.x;
    const int t    = threadIdx.x;
    const int wave = t >> 6;
    const int lane = t & 63;

    __shared__ __align__(16) float ne_s[16][516];   // chunk of 16 neighbors, padded
    __shared__ __align__(16) float g_s[HH * DD];
    __shared__ float part[4][16][HH];               // [wave][k][h]
    __shared__ float p_s[HH][16];
    __shared__ float c_s[HH];
    __shared__ float m_s[HH], l_s[HH], alpha_s[HH];

    // stage g (query-side projected vectors), 2048 floats
    {
        const float4* gs = (const float4*)(g + (long)bn * (HH * DD));
        float4 v0 = gs[t];
        float4 v1 = gs[t + 256];
        *(float4*)&g_s[t * 4]         = v0;
        *(float4*)&g_s[(t + 256) * 4] = v1;
    }
    // c[h] = q_h . bk_h   (wave w handles head w; 64 lanes x 2 elems = 128)
    {
        float2 q2 = *(const float2*)&q[(long)bn * DD + wave * DH + lane * 2];
        float2 b2 = *(const float2*)&bk[wave * DH + lane * 2];
        float cp = q2.x * b2.x + q2.y * b2.y;
#pragma unroll
        for (int off = 32; off >= 1; off >>= 1)
            cp += __shfl_xor(cp, off, 64);
        if (lane == 0) c_s[wave] = cp;
    }
    if (t < HH) { m_s[t] = -__builtin_inff(); l_s[t] = 0.f; }

    float wacc[8] = {};
    const int h_own = t >> 6;            // head owned in weighted-sum phase
    const int d8    = (t & 63) * 8;      // 8-float slice of D
    const int kk    = t & 15;            // neighbor within chunk (scores phase)
    const int rep   = t >> 4;            // D-slice 32 floats (scores phase)

    for (int ch = 0; ch < 2; ch++) {
        __syncthreads();
        // load chunk of 16 neighbor rows (contiguous 32 KB) into LDS
        {
            const float4* src = (const float4*)(ne + (long)bn * (KK_N * DD) + ch * (16 * DD));
#pragma unroll
            for (int i = 0; i < 8; i++) {
                int f = i * 256 + t;
                float4 v = src[f];
                *(float4*)&ne_s[f >> 7][(f & 127) * 4] = v;
            }
        }
        __syncthreads();
        // scores: 16 k x 4 h dot products of length 512, split 16 ways over D
        {
            float acc[HH] = {};
#pragma unroll
            for (int i = 0; i < 8; i++) {
                float4 nv = *(const float4*)&ne_s[kk][rep * 32 + i * 4];
#pragma unroll
                for (int h = 0; h < HH; h++) {
                    float4 gv = *(const float4*)&g_s[h * DD + rep * 32 + i * 4];
                    acc[h] = fmaf(nv.x, gv.x, acc[h]);
                    acc[h] = fmaf(nv.y, gv.y, acc[h]);
                    acc[h] = fmaf(nv.z, gv.z, acc[h]);
                    acc[h] = fmaf(nv.w, gv.w, acc[h]);
                }
            }
#pragma unroll
            for (int h = 0; h < HH; h++) {
                acc[h] += __shfl_xor(acc[h], 16, 64);
                acc[h] += __shfl_xor(acc[h], 32, 64);
            }
            if ((t & 48) == 0) {
#pragma unroll
                for (int h = 0; h < HH; h++) part[wave][kk][h] = acc[h];
            }
        }
        __syncthreads();
        // online softmax update (wave 0 only; lanes: k_i = bits 0..3, h = bits 4..5)
        if (t < 64) {
            int k_i = t & 15, h = t >> 4;
            float s = part[0][k_i][h] + part[1][k_i][h] + part[2][k_i][h]
                    + part[3][k_i][h] + c_s[h];
            if (mask[(long)bn * KK_N + ch * 16 + k_i] == 0) s = -1.0e9f;
            float mx = s;
#pragma unroll
            for (int off = 8; off >= 1; off >>= 1)
                mx = fmaxf(mx, __shfl_xor(mx, off, 64));
            float m_old = m_s[h];
            float m_new = fmaxf(m_old, mx);
            float p = expf(s - m_new);
            float sm = p;
#pragma unroll
            for (int off = 8; off >= 1; off >>= 1)
                sm += __shfl_xor(sm, off, 64);
            p_s[h][k_i] = p;
            if (k_i == 0) {
                float alpha = expf(m_old - m_new);
                alpha_s[h] = alpha;
                l_s[h] = l_s[h] * alpha + sm;
                m_s[h] = m_new;
            }
        }
        __syncthreads();
        // weighted accumulate: thread owns (h_own, 8 floats of D)
        {
            float alpha = alpha_s[h_own];
#pragma unroll
            for (int j = 0; j < 8; j++) wacc[j] *= alpha;
#pragma unroll
            for (int k2 = 0; k2 < 16; k2++) {
                float pk = p_s[h_own][k2];
                float4 n0 = *(const float4*)&ne_s[k2][d8];
                float4 n1 = *(const float4*)&ne_s[k2][d8 + 4];
                wacc[0] = fmaf(pk, n0.x, wacc[0]);
                wacc[1] = fmaf(pk, n0.y, wacc[1]);
                wacc[2] = fmaf(pk, n0.z, wacc[2]);
                wacc[3] = fmaf(pk, n0.w, wacc[3]);
                wacc[4] = fmaf(pk, n1.x, wacc[4]);
                wacc[5] = fmaf(pk, n1.y, wacc[5]);
                wacc[6] = fmaf(pk, n1.z, wacc[6]);
                wacc[7] = fmaf(pk, n1.w, wacc[7]);
            }
        }
    }
    // finalize: normalize and write wne[bn] (flat offset == t*8 by construction)
    float rl = 1.0f / l_s[h_own];
    float4 o0 = make_float4(wacc[0] * rl, wacc[1] * rl, wacc[2] * rl, wacc[3] * rl);
    float4 o1 = make_float4(wacc[4] * rl, wacc[5] * rl, wacc[6] * rl, wacc[7] * rl);
    float* dst = wne + (long)bn * (HH * DD) + t * 8;
    *(float4*)&dst[0] = o0;
    *(float4*)&dst[4] = o1;
}

// ---------------------------------------------------------------------------
extern "C" void kernel_launch(void* const* d_in, const int* in_sizes, int n_in,
                              void* d_out, int out_size, void* d_ws, size_t ws_size,
                              hipStream_t stream) {
    (void)in_sizes; (void)n_in; (void)out_size; (void)ws_size;
    const float* ne  = (const float*)d_in[0];
    const int*   msk = (const int*)  d_in[1];
    const float* x   = (const float*)d_in[2];
    const float* Wq  = (const float*)d_in[3];
    const float* bq  = (const float*)d_in[4];
    const float* Wk  = (const float*)d_in[5];
    const float* bk  = (const float*)d_in[6];
    const float* Wv  = (const float*)d_in[7];
    const float* bv  = (const float*)d_in[8];
    float* out = (float*)d_out;

    // workspace: q [4096*512] then g/wne [4096*4*512] (aliased) => ~42 MB
    float* q_ws = (float*)d_ws;
    float* g_ws = q_ws + (long)BN_TOT * DD;

    dim3 blk(256);
    // 1) q = x @ Wq^T + bq   (NT) — 128x64 tile, 8x4/thread, 256 blocks
    sgemm<true, 128, 64, 8, 4><<<dim3(8, 32, 1), blk, 0, stream>>>(
        x, DD, 0, Wq, DD, 0, q_ws, DD, 0, bq, 0, DD);
    // 2) g[:,h,:] = q_h @ Wk_h  (NN) — 128x128 tile, 8x8/thread, 512 blocks
    sgemm<false, 128, 128, 8, 8><<<dim3(4, 32, HH), blk, 0, stream>>>(
        q_ws, DD, DH, Wk, DD, DH * DD, g_ws, HH * DD, DD, nullptr, 0, DH);
    // 3) fused scores/softmax/weighted-sum -> wne (aliases g_ws)
    attn_fused<<<dim3(BN_TOT), blk, 0, stream>>>(ne, msk, q_ws, g_ws, bk, g_ws);
    // 4) out_h = wne_h @ Wv_h^T + bv_h  (NT) — 64x128 tile, 4x8/thread, 256 blocks
    sgemm<true, 64, 128, 4, 8><<<dim3(1, 64, HH), blk, 0, stream>>>(
        g_ws, HH * DD, DD, Wv, DD, DH * DD, out, DD, DH, bv, DH, DD);
}

// Round 4
// 489.098 us; speedup vs baseline: 1.0844x; 1.0844x over previous
//
#include <hip/hip_runtime.h>

// Problem constants
#define DD   512
#define KK_N 32
#define HH   4
#define DH   128
#define BN_TOT 4096

// ---------------------------------------------------------------------------
// Batched SGEMM, C[r][o] = sum_k A[r*lda+k] * Bop[o][k]   (no bias)
//   BT=true : B stored [N][K] row-major (B[o*ldb+k])   — "NT"
//   BT=false: B stored [K][N] row-major (B[k*ldb+o])   — "NN"
// 256 threads. Tile BMxBN, per-thread TMxTN, K-chunk 16, reg-prefetch pipeline.
// blockIdx.z decomposed: zlo = z & ((1<<ZBITS)-1), zhi = z >> ZBITS;
// operand base += zhi*b?1 + zlo*b?0.
// ---------------------------------------------------------------------------
template<bool BT, int BM, int BN, int TM, int TN, int ZBITS>
__global__ __launch_bounds__(256)
void sgemm(const float* __restrict__ A, int lda, int bA1, int bA0,
           const float* __restrict__ B, int ldb, int bB1, int bB0,
           float* __restrict__ C, int ldc, int bC1, int bC0,
           int Kd)
{
    constexpr int BK = 16;
    constexpr int KG = BK / 4;
    constexpr int A_LOADS = (BM * BK) / (4 * 256);
    constexpr int B_LOADS = (BN * BK) / (4 * 256);
    constexpr int NTX = BN / TN;

    const int zlo = blockIdx.z & ((1 << ZBITS) - 1);
    const int zhi = blockIdx.z >> ZBITS;
    A += (long)zhi * bA1 + (long)zlo * bA0;
    B += (long)zhi * bB1 + (long)zlo * bB0;
    C += (long)zhi * bC1 + (long)zlo * bC0;

    __shared__ __align__(16) float As[BK][BM + 4];
    __shared__ __align__(16) float Bs[BK][BN + 4];

    const int t  = threadIdx.x;
    const int tx = t % NTX;
    const int ty = t / NTX;
    const int rbase = blockIdx.y * BM;
    const int obase = blockIdx.x * BN;

    float4 av[A_LOADS], bv[B_LOADS];
    auto loadAB = [&](int k0) {
#pragma unroll
        for (int i = 0; i < A_LOADS; i++) {
            int s = t + i * 256, row = s / KG, kg = s % KG;
            av[i] = *(const float4*)&A[(long)(rbase + row) * lda + k0 + kg * 4];
        }
#pragma unroll
        for (int i = 0; i < B_LOADS; i++) {
            int s = t + i * 256;
            if (BT) {
                int row = s / KG, kg = s % KG;
                bv[i] = *(const float4*)&B[(long)(obase + row) * ldb + k0 + kg * 4];
            } else {
                int kr = s / (BN / 4), oc = s % (BN / 4);
                bv[i] = *(const float4*)&B[(long)(k0 + kr) * ldb + obase + oc * 4];
            }
        }
    };

    float acc[TM][TN] = {};
    loadAB(0);

    for (int k0 = 0; k0 < Kd; k0 += BK) {
        __syncthreads();      // previous chunk's LDS reads done
        // ---- stage regs -> LDS ----
#pragma unroll
        for (int i = 0; i < A_LOADS; i++) {
            int s = t + i * 256, row = s / KG, kg = s % KG;
            const float* ap = (const float*)&av[i];
#pragma unroll
            for (int j = 0; j < 4; j++) As[kg * 4 + j][row] = ap[j];
        }
#pragma unroll
        for (int i = 0; i < B_LOADS; i++) {
            int s = t + i * 256;
            if (BT) {
                int row = s / KG, kg = s % KG;
                const float* bp = (const float*)&bv[i];
#pragma unroll
                for (int j = 0; j < 4; j++) Bs[kg * 4 + j][row] = bp[j];
            } else {
                int kr = s / (BN / 4), oc = s % (BN / 4);
                *(float4*)&Bs[kr][oc * 4] = bv[i];
            }
        }
        __syncthreads();
        // ---- prefetch next chunk into freed regs (overlaps compute) ----
        if (k0 + BK < Kd) loadAB(k0 + BK);
        // ---- compute ----
#pragma unroll
        for (int kk = 0; kk < BK; kk++) {
            float a[TM], b[TN];
#pragma unroll
            for (int im = 0; im < TM / 4; im++) {
                float4 v = *(const float4*)&As[kk][ty * TM + im * 4];
                a[im*4+0] = v.x; a[im*4+1] = v.y; a[im*4+2] = v.z; a[im*4+3] = v.w;
            }
#pragma unroll
            for (int in = 0; in < TN / 4; in++) {
                float4 v = *(const float4*)&Bs[kk][tx * TN + in * 4];
                b[in*4+0] = v.x; b[in*4+1] = v.y; b[in*4+2] = v.z; b[in*4+3] = v.w;
            }
#pragma unroll
            for (int i = 0; i < TM; i++)
#pragma unroll
                for (int j = 0; j < TN; j++)
                    acc[i][j] = fmaf(a[i], b[j], acc[i][j]);
        }
    }

    // ---- epilogue (no bias) ----
#pragma unroll
    for (int i = 0; i < TM; i++) {
#pragma unroll
        for (int in = 0; in < TN / 4; in++) {
            float4 o;
            o.x = acc[i][in*4+0];
            o.y = acc[i][in*4+1];
            o.z = acc[i][in*4+2];
            o.w = acc[i][in*4+3];
            *(float4*)&C[(long)(rbase + ty * TM + i) * ldc + obase + tx * TN + in * 4] = o;
        }
    }
}

// ---------------------------------------------------------------------------
// o[i] = a[i] + b[i] + bias[i mod 512]   (float4 units; row length 128 float4)
// ---------------------------------------------------------------------------
__global__ __launch_bounds__(256)
void add2_bias(const float4* __restrict__ a, const float4* __restrict__ b,
               const float4* __restrict__ bias, float4* __restrict__ o, int n4)
{
    for (int i = blockIdx.x * 256 + threadIdx.x; i < n4; i += gridDim.x * 256) {
        float4 va = a[i], vb = b[i], vc = bias[i & 127];
        float4 r;
        r.x = va.x + vb.x + vc.x;
        r.y = va.y + vb.y + vc.y;
        r.z = va.z + vb.z + vc.z;
        r.w = va.w + vb.w + vc.w;
        o[i] = r;
    }
}

// ---------------------------------------------------------------------------
// Fused scores -> masked online softmax -> attention-weighted embedding sum.
// One block per (b,n). wne may alias g (read fully before written, same block).
// ---------------------------------------------------------------------------
__global__ __launch_bounds__(256)
void attn_fused(const float* __restrict__ ne,    // [BN][32][512]
                const int*   __restrict__ mask,  // [BN][32]
                const float* __restrict__ q,     // [BN][512]
                const float* g,                  // [BN][4][512]  (no restrict: aliases wne)
                const float* __restrict__ bk,    // [512]
                float* wne)                      // [BN][4][512]
{
    const int bn   = blockIdx.x;
    const int t    = threadIdx.x;
    const int wave = t >> 6;
    const int lane = t & 63;

    __shared__ __align__(16) float ne_s[16][516];   // chunk of 16 neighbors, padded
    __shared__ __align__(16) float g_s[HH * DD];
    __shared__ float part[4][16][HH];               // [wave][k][h]
    __shared__ float p_s[HH][16];
    __shared__ float c_s[HH];
    __shared__ float m_s[HH], l_s[HH], alpha_s[HH];

    // stage g (query-side projected vectors), 2048 floats
    {
        const float4* gs = (const float4*)(g + (long)bn * (HH * DD));
        float4 v0 = gs[t];
        float4 v1 = gs[t + 256];
        *(float4*)&g_s[t * 4]         = v0;
        *(float4*)&g_s[(t + 256) * 4] = v1;
    }
    // c[h] = q_h . bk_h   (wave w handles head w; 64 lanes x 2 elems = 128)
    {
        float2 q2 = *(const float2*)&q[(long)bn * DD + wave * DH + lane * 2];
        float2 b2 = *(const float2*)&bk[wave * DH + lane * 2];
        float cp = q2.x * b2.x + q2.y * b2.y;
#pragma unroll
        for (int off = 32; off >= 1; off >>= 1)
            cp += __shfl_xor(cp, off, 64);
        if (lane == 0) c_s[wave] = cp;
    }
    if (t < HH) { m_s[t] = -__builtin_inff(); l_s[t] = 0.f; }

    float wacc[8] = {};
    const int h_own = t >> 6;            // head owned in weighted-sum phase
    const int d8    = (t & 63) * 8;      // 8-float slice of D
    const int kk    = t & 15;            // neighbor within chunk (scores phase)
    const int rep   = t >> 4;            // D-slice 32 floats (scores phase)

    for (int ch = 0; ch < 2; ch++) {
        __syncthreads();
        // load chunk of 16 neighbor rows (contiguous 32 KB) into LDS
        {
            const float4* src = (const float4*)(ne + (long)bn * (KK_N * DD) + ch * (16 * DD));
#pragma unroll
            for (int i = 0; i < 8; i++) {
                int f = i * 256 + t;
                float4 v = src[f];
                *(float4*)&ne_s[f >> 7][(f & 127) * 4] = v;
            }
        }
        __syncthreads();
        // scores: 16 k x 4 h dot products of length 512, split 16 ways over D
        {
            float acc[HH] = {};
#pragma unroll
            for (int i = 0; i < 8; i++) {
                float4 nv = *(const float4*)&ne_s[kk][rep * 32 + i * 4];
#pragma unroll
                for (int h = 0; h < HH; h++) {
                    float4 gv = *(const float4*)&g_s[h * DD + rep * 32 + i * 4];
                    acc[h] = fmaf(nv.x, gv.x, acc[h]);
                    acc[h] = fmaf(nv.y, gv.y, acc[h]);
                    acc[h] = fmaf(nv.z, gv.z, acc[h]);
                    acc[h] = fmaf(nv.w, gv.w, acc[h]);
                }
            }
#pragma unroll
            for (int h = 0; h < HH; h++) {
                acc[h] += __shfl_xor(acc[h], 16, 64);
                acc[h] += __shfl_xor(acc[h], 32, 64);
            }
            if ((t & 48) == 0) {
#pragma unroll
                for (int h = 0; h < HH; h++) part[wave][kk][h] = acc[h];
            }
        }
        __syncthreads();
        // online softmax update (wave 0 only; lanes: k_i = bits 0..3, h = bits 4..5)
        if (t < 64) {
            int k_i = t & 15, h = t >> 4;
            float s = part[0][k_i][h] + part[1][k_i][h] + part[2][k_i][h]
                    + part[3][k_i][h] + c_s[h];
            if (mask[(long)bn * KK_N + ch * 16 + k_i] == 0) s = -1.0e9f;
            float mx = s;
#pragma unroll
            for (int off = 8; off >= 1; off >>= 1)
                mx = fmaxf(mx, __shfl_xor(mx, off, 64));
            float m_old = m_s[h];
            float m_new = fmaxf(m_old, mx);
            float p = expf(s - m_new);
            float sm = p;
#pragma unroll
            for (int off = 8; off >= 1; off >>= 1)
                sm += __shfl_xor(sm, off, 64);
            p_s[h][k_i] = p;
            if (k_i == 0) {
                float alpha = expf(m_old - m_new);
                alpha_s[h] = alpha;
                l_s[h] = l_s[h] * alpha + sm;
                m_s[h] = m_new;
            }
        }
        __syncthreads();
        // weighted accumulate: thread owns (h_own, 8 floats of D)
        {
            float alpha = alpha_s[h_own];
#pragma unroll
            for (int j = 0; j < 8; j++) wacc[j] *= alpha;
#pragma unroll
            for (int k2 = 0; k2 < 16; k2++) {
                float pk = p_s[h_own][k2];
                float4 n0 = *(const float4*)&ne_s[k2][d8];
                float4 n1 = *(const float4*)&ne_s[k2][d8 + 4];
                wacc[0] = fmaf(pk, n0.x, wacc[0]);
                wacc[1] = fmaf(pk, n0.y, wacc[1]);
                wacc[2] = fmaf(pk, n0.z, wacc[2]);
                wacc[3] = fmaf(pk, n0.w, wacc[3]);
                wacc[4] = fmaf(pk, n1.x, wacc[4]);
                wacc[5] = fmaf(pk, n1.y, wacc[5]);
                wacc[6] = fmaf(pk, n1.z, wacc[6]);
                wacc[7] = fmaf(pk, n1.w, wacc[7]);
            }
        }
    }
    // finalize: normalize and write wne[bn] (flat offset == t*8 by construction)
    float rl = 1.0f / l_s[h_own];
    float4 o0 = make_float4(wacc[0] * rl, wacc[1] * rl, wacc[2] * rl, wacc[3] * rl);
    float4 o1 = make_float4(wacc[4] * rl, wacc[5] * rl, wacc[6] * rl, wacc[7] * rl);
    float* dst = wne + (long)bn * (HH * DD) + t * 8;
    *(float4*)&dst[0] = o0;
    *(float4*)&dst[4] = o1;
}

// ---------------------------------------------------------------------------
extern "C" void kernel_launch(void* const* d_in, const int* in_sizes, int n_in,
                              void* d_out, int out_size, void* d_ws, size_t ws_size,
                              hipStream_t stream) {
    (void)in_sizes; (void)n_in; (void)out_size; (void)ws_size;
    const float* ne  = (const float*)d_in[0];
    const int*   msk = (const int*)  d_in[1];
    const float* x   = (const float*)d_in[2];
    const float* Wq  = (const float*)d_in[3];
    const float* bq  = (const float*)d_in[4];
    const float* Wk  = (const float*)d_in[5];
    const float* bk  = (const float*)d_in[6];
    const float* Wv  = (const float*)d_in[7];
    const float* bv  = (const float*)d_in[8];
    float* out = (float*)d_out;

    const long NQ = (long)BN_TOT * DD;          // 2M elems
    float* q_ws  = (float*)d_ws;                // [4096][512]
    float* g_ws  = q_ws + NQ;                   // [4096][4][512] (g, then wne)
    float* qpart = g_ws + (long)BN_TOT * HH * DD;  // 2 x [4096][512]
    float* opart = qpart + 2 * NQ;              // 2 x [4096][512]

    dim3 blk(256);
    // 1) qpart[ks] = x[:, ks*256:] @ Wq[:, ks*256:]^T   (NT, split-K=2)
    //    128x64 tile, 8x4/thread, 512 blocks
    sgemm<true, 128, 64, 8, 4, 1><<<dim3(8, 32, 2), blk, 0, stream>>>(
        x, DD, 0, 256, Wq, DD, 0, 256, qpart, DD, 0, (int)NQ, 256);
    // 1b) q = qpart0 + qpart1 + bq
    add2_bias<<<dim3(512), blk, 0, stream>>>(
        (const float4*)qpart, (const float4*)(qpart + NQ),
        (const float4*)bq, (float4*)q_ws, (int)(NQ / 4));
    // 2) g[:,h,:] = q_h @ Wk_h   (NN) — 128x128 tile, 8x8/thread, 512 blocks
    sgemm<false, 128, 128, 8, 8, 0><<<dim3(4, 32, HH), blk, 0, stream>>>(
        q_ws, DD, DH, 0, Wk, DD, DH * DD, 0, g_ws, HH * DD, DD, 0, DH);
    // 3) fused scores/softmax/weighted-sum -> wne (aliases g_ws)
    attn_fused<<<dim3(BN_TOT), blk, 0, stream>>>(ne, msk, q_ws, g_ws, bk, g_ws);
    // 4) opart[ks][:, h*128+o] = wne_h[:, ks*256:] @ Wv_h[:, ks*256:]^T
    //    (NT, split-K=2 per head; z = head*2 + ks) — 128x64 tile, 512 blocks
    sgemm<true, 128, 64, 8, 4, 1><<<dim3(2, 32, 2 * HH), blk, 0, stream>>>(
        g_ws, HH * DD, DD, 256, Wv, DD, DH * DD, 256, opart, DD, DH, (int)NQ, 256);
    // 4b) out = opart0 + opart1 + bv
    add2_bias<<<dim3(512), blk, 0, stream>>>(
        (const float4*)opart, (const float4*)(opart + NQ),
        (const float4*)bv, (float4*)out, (int)(NQ / 4));
}